// Round 16
// baseline (1006.058 us; speedup 1.0000x reference)
//
#include <hip/hip_runtime.h>

#define NB 1024   // boxes
#define NC 151    // classes
#define NCP 152   // padded probs row stride (16B-aligned)
#define DF 4096   // feature dim
typedef unsigned long long u64;

// ---- GEMM + fused softmax: dists = fmap @ W + b; probs = softmax(dists), col0=0 ----
// K split in QUARTERS across 768 threads; f64 partials combined in fixed order.
__global__ __launch_bounds__(768) void gemm_sm_kernel(
    const float* __restrict__ fmap, const float* __restrict__ W,
    const float* __restrict__ bias, float* __restrict__ dists,
    float* __restrict__ probs) {
  __shared__ float sf[4 * DF];           // 64 KiB
  __shared__ double spart[4][4][NC];     // 19.3 KB f64 partials [quarter][row][class]
  __shared__ float sdist[4][NCP];
  __shared__ float smx[4], ssum[4];
  int r0 = blockIdx.x * 4;
  const float4* src = (const float4*)(fmap + (size_t)r0 * DF);
  for (int i = threadIdx.x; i < 4 * (DF / 4); i += 768) {
    int r = i >> 10;       // row 0..3
    int q = i & 1023;      // float4 index within row
    float4 v = src[i];
    sf[(4 * q + 0) * 4 + r] = v.x;
    sf[(4 * q + 1) * 4 + r] = v.y;
    sf[(4 * q + 2) * 4 + r] = v.z;
    sf[(4 * q + 3) * 4 + r] = v.w;
  }
  __syncthreads();
  {
    int qr = threadIdx.x / 192;          // K-quarter 0..3
    int ch = threadIdx.x - qr * 192;
    if (ch < NC) {
      double a0 = 0.0, a1 = 0.0, a2 = 0.0, a3 = 0.0;
      const float4* sf4 = (const float4*)sf + qr * (DF / 4);
      const float* w = W + ch + (size_t)qr * (DF / 4) * NC;
#pragma unroll 8
      for (int d = 0; d < DF / 4; ++d) {
        float4 f = sf4[d];                       // broadcast across wave
        double wv = (double)w[(size_t)d * NC];   // coalesced across threads
        a0 += (double)f.x * wv;
        a1 += (double)f.y * wv;
        a2 += (double)f.z * wv;
        a3 += (double)f.w * wv;
      }
      spart[qr][0][ch] = a0;
      spart[qr][1][ch] = a1;
      spart[qr][2][ch] = a2;
      spart[qr][3][ch] = a3;
    }
  }
  __syncthreads();
  int c = threadIdx.x;
  if (c < NC) {
    float b = bias[c];
    float v0 = (float)(((spart[0][0][c] + spart[1][0][c]) + spart[2][0][c]) + spart[3][0][c]) + b;
    float v1 = (float)(((spart[0][1][c] + spart[1][1][c]) + spart[2][1][c]) + spart[3][1][c]) + b;
    float v2 = (float)(((spart[0][2][c] + spart[1][2][c]) + spart[2][2][c]) + spart[3][2][c]) + b;
    float v3 = (float)(((spart[0][3][c] + spart[1][3][c]) + spart[2][3][c]) + spart[3][3][c]) + b;
    dists[(size_t)(r0 + 0) * NC + c] = v0;
    dists[(size_t)(r0 + 1) * NC + c] = v1;
    dists[(size_t)(r0 + 2) * NC + c] = v2;
    dists[(size_t)(r0 + 3) * NC + c] = v3;
    sdist[0][c] = v0; sdist[1][c] = v1; sdist[2][c] = v2; sdist[3][c] = v3;
  }
  __syncthreads();
  // wave 0 reproduces the original softmax reduce order exactly
  if (threadIdx.x < 64) {
    int t = threadIdx.x;
#pragma unroll
    for (int r = 0; r < 4; ++r) {
      float v0 = sdist[r][t];
      float v1 = sdist[r][t + 64];
      float v2 = (t + 128 < NC) ? sdist[r][t + 128] : -3.0e38f;
      float m = fmaxf(fmaxf(v0, v1), v2);
      for (int off = 32; off; off >>= 1) m = fmaxf(m, __shfl_down(m, off));
      m = __shfl(m, 0);
      float e0 = expf(v0 - m), e1 = expf(v1 - m);
      float e2 = (t + 128 < NC) ? expf(v2 - m) : 0.0f;
      float s = e0 + e1 + e2;
      for (int off = 32; off; off >>= 1) s += __shfl_down(s, off);
      s = __shfl(s, 0);
      if (t == 0) { smx[r] = m; ssum[r] = s; }
    }
  }
  __syncthreads();
  if (c < NC) {
#pragma unroll
    for (int r = 0; r < 4; ++r) {
      float p = (c == 0) ? 0.0f : (expf(sdist[r][c] - smx[r]) / ssum[r]);
      probs[(size_t)(r0 + r) * NCP + c] = p;
    }
  }
  if (threadIdx.x == 0) {
#pragma unroll
    for (int r = 0; r < 4; ++r) probs[(size_t)(r0 + r) * NCP + NC] = -1.0f;  // pad
  }
}

// ---------------- precompute overlap bitmask: mask[cl][b] = 1024 bits ----------------
__global__ __launch_bounds__(256) void mask_kernel(
    const float* __restrict__ boxes, u64* __restrict__ mask) {
#pragma clang fp contract(off)
  int cl = blockIdx.x >> 4;          // 151 classes
  int bb = (blockIdx.x & 15) * 64;   // 16 b-groups of 64
  __shared__ float4 sbox[NB];
  __shared__ float sarea[NB];
  for (int i = threadIdx.x; i < NB; i += 256) {
    float4 b = *(const float4*)(boxes + ((size_t)i * NC + cl) * 4);
    sbox[i] = b;
    sarea[i] = (b.z - b.x + 1.0f) * (b.w - b.y + 1.0f);
  }
  __syncthreads();
  int wv = threadIdx.x >> 6, lane = threadIdx.x & 63;
  for (int j = 0; j < 16; ++j) {
    int b = bb + wv * 16 + j;
    float4 B = sbox[b];
    float areaB = sarea[b];
    u64 myword = 0;
#pragma unroll
    for (int k = 0; k < 16; ++k) {
      int r = k * 64 + lane;
      float4 R = sbox[r];
      float ix = fminf(B.z, R.z) - fmaxf(B.x, R.x) + 1.0f;
      float iy = fminf(B.w, R.w) - fmaxf(B.y, R.y) + 1.0f;
      ix = fmaxf(ix, 0.0f);
      iy = fmaxf(iy, 0.0f);
      float inter = ix * iy;
      float uni = sarea[r] + areaB - inter;
      float iou = inter / uni;            // IEEE div — must match numpy exactly
      u64 bal = __ballot(iou >= 0.5f);
      if (lane == k) myword = bal;
    }
    if (lane < 16) mask[((size_t)cl * NB + b) * 16 + lane] = myword;
  }
}

// ---------------- greedy commit: FOUR waves, top-2 promote, 1 barrier/iter ----------------
template <int CTRL, int ROWMASK>
__device__ __forceinline__ float dpp_max_step(float v) {
  int x = __float_as_int(v);
  int t = __builtin_amdgcn_update_dpp(x, x, CTRL, ROWMASK, 0xf, false);
  return fmaxf(v, __int_as_float(t));
}

// canonical gfx9 wave64 max reduce; result broadcast via readlane(63)
__device__ __forceinline__ float wave_max(float v) {
  v = dpp_max_step<0x111, 0xf>(v);  // row_shr:1
  v = dpp_max_step<0x112, 0xf>(v);  // row_shr:2
  v = dpp_max_step<0x114, 0xf>(v);  // row_shr:4
  v = dpp_max_step<0x118, 0xf>(v);  // row_shr:8
  v = dpp_max_step<0x142, 0xa>(v);  // row_bcast:15
  v = dpp_max_step<0x143, 0xc>(v);  // row_bcast:31
  return __int_as_float(__builtin_amdgcn_readlane(__float_as_int(v), 63));
}

// top-2 scan of a probs row (optionally masking zeroed classes to 0); strict >,
// first-index ties. (m1,a1)=first argmax; (m2,a2)=exact next-first-argmax sans a1.
template <bool MASKED>
__device__ __forceinline__ void scan_top2(const float* __restrict__ pp,
                                          u64 z0, u64 z1, u64 z2,
                                          float& m1o, int& a1o, float& m2o, int& a2o) {
  const float4* p4 = (const float4*)pp;
  float m1 = -1.0f, m2 = -1.0f;
  int a1 = 0, a2 = 0;
#pragma unroll 2
  for (int q = 0; q < NCP / 4; ++q) {
    float4 v = p4[q];
    unsigned bits = 0;
    if (MASKED) {
      u64 z = q < 16 ? z0 : (q < 32 ? z1 : z2);
      bits = (unsigned)(z >> ((q & 15) * 4)) & 0xFu;
    }
    float e0 = (MASKED && (bits & 1u)) ? 0.0f : v.x;
    float e1 = (MASKED && (bits & 2u)) ? 0.0f : v.y;
    float e2 = (MASKED && (bits & 4u)) ? 0.0f : v.z;
    float e3 = (MASKED && (bits & 8u)) ? 0.0f : v.w;
    int c0 = q * 4;
    if (e0 > m1) { m2 = m1; a2 = a1; m1 = e0; a1 = c0; } else if (e0 > m2) { m2 = e0; a2 = c0; }
    if (e1 > m1) { m2 = m1; a2 = a1; m1 = e1; a1 = c0 + 1; } else if (e1 > m2) { m2 = e1; a2 = c0 + 1; }
    if (e2 > m1) { m2 = m1; a2 = a1; m1 = e2; a1 = c0 + 2; } else if (e2 > m2) { m2 = e2; a2 = c0 + 2; }
    if (e3 > m1) { m2 = m1; a2 = a1; m1 = e3; a1 = c0 + 3; } else if (e3 > m2) { m2 = e3; a2 = c0 + 3; }
  }
  m1o = m1; a1o = a1; m2o = m2; a2o = a2;
}

__global__ __launch_bounds__(256, 1) void greedy_kernel(
    const float* __restrict__ probs, const u64* __restrict__ mask,
    float* __restrict__ out_preds) {
  __shared__ u64 smask[NB * 16];      // 128 KB: prefetched argmax-class columns
  __shared__ unsigned pcls[NB];       // 4 KB: class tag of each prefetched column
  __shared__ u64 skey[2][4];          // parity-double-buffered per-wave keys

  int tid = threadIdx.x;
  int w = tid >> 6, lane = tid & 63;
  int rbase = tid << 2;               // my rows: rbase+0..3
  int widx = tid >> 4;                // my mask word index (row>>6 of my rows)
  int hsh = (tid & 15) << 2;          // shift for my 4 bits within the word

  float rm[4], rm2[4];                // rm2 < 0 => second-max invalid
  int ra[4], ra2[4], cm[4];
  u64 zb0[4], zb1[4], zb2[4];
  unsigned committed = 0;

  // ---- init: top-2 scan of my 4 rows; publish initial argmax class ----
#pragma unroll
  for (int r = 0; r < 4; ++r) {
    scan_top2<false>(probs + (size_t)(rbase + r) * NCP, 0, 0, 0,
                     rm[r], ra[r], rm2[r], ra2[r]);
    cm[r] = 0; zb0[r] = 0; zb1[r] = 0; zb2[r] = 0;
    pcls[rbase + r] = (unsigned)ra[r];
  }
  __syncthreads();

  // ---- prefetch 1024 columns (b, ra0[b]) into LDS ----
  for (int j = 0; j < NB; j += 16) {
    int col = j + (tid >> 4);
    int wd = tid & 15;
    unsigned pc = pcls[col];
    smask[(col << 4) | wd] = mask[(((size_t)pc << 10) | (size_t)col) * 16 + wd];
  }
  __syncthreads();

  for (int it = 0; it < NB; ++it) {
    int par = it & 1;

    // ---- local argmax over my 4 rows (ascending, strict > => smallest row on tie) ----
    float bv = rm[0];
    int bp = ra[0];                  // packed (r<<8)|ra
#pragma unroll
    for (int r = 1; r < 4; ++r) {
      int p = (r << 8) | ra[r];
      bool t = rm[r] > bv;
      bv = t ? rm[r] : bv;
      bp = t ? p : bp;
    }

    // ---- per-wave winner ----
    float wmax = wave_max(bv);
    u64 ball = __ballot(bv == wmax);
    int wl = __ffsll(ball) - 1;      // smallest lane = smallest row in wave
    int pw = __builtin_amdgcn_readlane(bp, wl);
    int gw = (w << 8) | (wl << 2) | (pw >> 8);   // wave-winner row
    int clw = pw & 0xff;
    unsigned ub = __float_as_uint(wmax);
    unsigned su = ((int)ub >= 0) ? (ub | 0x80000000u) : ~ub;  // monotone u32 of float
    u64 key = ((u64)su << 32) | ((u64)(NB - 1 - gw) << 8) | (unsigned)clw;
    if (lane == 0) skey[par][w] = key;
    __syncthreads();

    // ---- global winner (all waves redundantly; broadcast LDS reads) ----
    u64 k0 = skey[par][0], k1 = skey[par][1], k2 = skey[par][2], k3 = skey[par][3];
    u64 ka = k0 > k1 ? k0 : k1;
    u64 kb = k2 > k3 ? k2 : k3;
    u64 kk = ka > kb ? ka : kb;
    int b = NB - 1 - (int)((kk >> 8) & 0x3FFu);
    int cl = (int)(kk & 0xFFu);
    // endgame guard: all rows at -1 -> reference flat argmax picks (0,0)
    if ((unsigned)(kk >> 32) < 0x80000000u) cl = 0;

    // ---- mask word: issue LDS read immediately; rare uniform fallback to global ----
    u64 word = smask[(b << 4) | widx];
    unsigned pc = pcls[b];
    if ((unsigned)cl != pc) {
      word = mask[(((size_t)cl << 10) | (size_t)b) * 16 + widx];
    }
    unsigned hits = (unsigned)(word >> hsh) & 0xFu;

    // per-word bit of class cl (uniform), branch-free
    int wi = cl >> 6;
    u64 bmv = 1ull << (cl & 63);
    u64 m0 = (wi == 0) ? bmv : 0, m1 = (wi == 1) ? bmv : 0, m2 = (wi == 2) ? bmv : 0;

    bool meT = (tid == (b >> 2));
    int blo = b & 3;

    // ---- update my 4 rows ----
    unsigned need = 0;
#pragma unroll
    for (int r = 0; r < 4; ++r) {
      unsigned rb = 1u << r;
      bool hit = (hits & rb) != 0;
      if (r == blo) {                // scalar compare (blo uniform)
        if (meT) {
          committed |= rb; rm[r] = -1.0f; rm2[r] = -3.0f; cm[r] = cl; hit = false;
        }
      }
      if (hit) {
        if (committed & rb) {
          // committed row: -1 everywhere except re-zeroed cols (0)
          if (rm[r] < 0.0f) { rm[r] = 0.0f; ra[r] = cl; }
          else if (cl < ra[r]) ra[r] = cl;
        } else {
          zb0[r] |= m0; zb1[r] |= m1; zb2[r] |= m2;
          if (rm2[r] >= 0.0f && ra2[r] == cl) rm2[r] = -3.0f;  // second killed
          if (ra[r] == cl) {                                   // argmax killed
            if (rm2[r] >= 0.0f) {                              // promote (exact)
              rm[r] = rm2[r]; ra[r] = ra2[r]; rm2[r] = -3.0f;
            } else {
              need |= rb;                                      // both dead: rescan
            }
          }
        }
      }
    }
    // per-wave rescan branch (no barrier inside -> waves independent)
    if (__ballot(need != 0)) {
#pragma unroll
      for (int r = 0; r < 4; ++r) {
        if (need & (1u << r))
          scan_top2<true>(probs + (size_t)(rbase + r) * NCP,
                          zb0[r], zb1[r], zb2[r],
                          rm[r], ra[r], rm2[r], ra2[r]);
      }
    }
  }

  // ---- write commits ----
#pragma unroll
  for (int r = 0; r < 4; ++r)
    out_preds[rbase + r] = (float)cm[r];
}

// ---------------- host ----------------
extern "C" void kernel_launch(void* const* d_in, const int* in_sizes, int n_in,
                              void* d_out, int out_size, void* d_ws, size_t ws_size,
                              hipStream_t stream) {
  const float* obj_fmap = (const float*)d_in[0];  // [NB, DF]
  const float* W_out    = (const float*)d_in[1];  // [DF, NC]
  const float* b_out    = (const float*)d_in[2];  // [NC]
  const float* boxes    = (const float*)d_in[3];  // [NB, NC, 4]

  float* out_dists = (float*)d_out;            // NB*NC
  float* out_preds = (float*)d_out + NB * NC;  // NB (as float)

  float* probs = (float*)d_ws;                     // NB*NCP floats (622,592 B)
  u64*   mask  = (u64*)(probs + (size_t)NB * NCP); // NC*NB*16 u64 (19.8 MB)

  gemm_sm_kernel<<<NB / 4, 768, 0, stream>>>(obj_fmap, W_out, b_out, out_dists, probs);
  mask_kernel<<<NC * 16, 256, 0, stream>>>(boxes, mask);
  greedy_kernel<<<1, 256, 0, stream>>>(probs, mask, out_preds);
}

// Round 17
// 975.274 us; speedup vs baseline: 1.0316x; 1.0316x over previous
//
#include <hip/hip_runtime.h>

#define NB 1024   // boxes
#define NC 151    // classes
#define NCP 152   // padded probs row stride (16B-aligned)
#define DF 4096   // feature dim
typedef unsigned long long u64;

// ---- GEMM + fused softmax: dists = fmap @ W + b; probs = softmax(dists), col0=0 ----
// K split in QUARTERS across 768 threads; f64 partials combined in fixed order.
__global__ __launch_bounds__(768) void gemm_sm_kernel(
    const float* __restrict__ fmap, const float* __restrict__ W,
    const float* __restrict__ bias, float* __restrict__ dists,
    float* __restrict__ probs) {
  __shared__ float sf[4 * DF];           // 64 KiB
  __shared__ double spart[4][4][NC];     // 19.3 KB f64 partials [quarter][row][class]
  __shared__ float sdist[4][NCP];
  __shared__ float smx[4], ssum[4];
  int r0 = blockIdx.x * 4;
  const float4* src = (const float4*)(fmap + (size_t)r0 * DF);
  for (int i = threadIdx.x; i < 4 * (DF / 4); i += 768) {
    int r = i >> 10;       // row 0..3
    int q = i & 1023;      // float4 index within row
    float4 v = src[i];
    sf[(4 * q + 0) * 4 + r] = v.x;
    sf[(4 * q + 1) * 4 + r] = v.y;
    sf[(4 * q + 2) * 4 + r] = v.z;
    sf[(4 * q + 3) * 4 + r] = v.w;
  }
  __syncthreads();
  {
    int qr = threadIdx.x / 192;          // K-quarter 0..3
    int ch = threadIdx.x - qr * 192;
    if (ch < NC) {
      double a0 = 0.0, a1 = 0.0, a2 = 0.0, a3 = 0.0;
      const float4* sf4 = (const float4*)sf + qr * (DF / 4);
      const float* w = W + ch + (size_t)qr * (DF / 4) * NC;
#pragma unroll 8
      for (int d = 0; d < DF / 4; ++d) {
        float4 f = sf4[d];                       // broadcast across wave
        double wv = (double)w[(size_t)d * NC];   // coalesced across threads
        a0 += (double)f.x * wv;
        a1 += (double)f.y * wv;
        a2 += (double)f.z * wv;
        a3 += (double)f.w * wv;
      }
      spart[qr][0][ch] = a0;
      spart[qr][1][ch] = a1;
      spart[qr][2][ch] = a2;
      spart[qr][3][ch] = a3;
    }
  }
  __syncthreads();
  int c = threadIdx.x;
  if (c < NC) {
    float b = bias[c];
    float v0 = (float)(((spart[0][0][c] + spart[1][0][c]) + spart[2][0][c]) + spart[3][0][c]) + b;
    float v1 = (float)(((spart[0][1][c] + spart[1][1][c]) + spart[2][1][c]) + spart[3][1][c]) + b;
    float v2 = (float)(((spart[0][2][c] + spart[1][2][c]) + spart[2][2][c]) + spart[3][2][c]) + b;
    float v3 = (float)(((spart[0][3][c] + spart[1][3][c]) + spart[2][3][c]) + spart[3][3][c]) + b;
    dists[(size_t)(r0 + 0) * NC + c] = v0;
    dists[(size_t)(r0 + 1) * NC + c] = v1;
    dists[(size_t)(r0 + 2) * NC + c] = v2;
    dists[(size_t)(r0 + 3) * NC + c] = v3;
    sdist[0][c] = v0; sdist[1][c] = v1; sdist[2][c] = v2; sdist[3][c] = v3;
  }
  __syncthreads();
  // wave 0 reproduces the original softmax reduce order exactly
  if (threadIdx.x < 64) {
    int t = threadIdx.x;
#pragma unroll
    for (int r = 0; r < 4; ++r) {
      float v0 = sdist[r][t];
      float v1 = sdist[r][t + 64];
      float v2 = (t + 128 < NC) ? sdist[r][t + 128] : -3.0e38f;
      float m = fmaxf(fmaxf(v0, v1), v2);
      for (int off = 32; off; off >>= 1) m = fmaxf(m, __shfl_down(m, off));
      m = __shfl(m, 0);
      float e0 = expf(v0 - m), e1 = expf(v1 - m);
      float e2 = (t + 128 < NC) ? expf(v2 - m) : 0.0f;
      float s = e0 + e1 + e2;
      for (int off = 32; off; off >>= 1) s += __shfl_down(s, off);
      s = __shfl(s, 0);
      if (t == 0) { smx[r] = m; ssum[r] = s; }
    }
  }
  __syncthreads();
  if (c < NC) {
#pragma unroll
    for (int r = 0; r < 4; ++r) {
      float p = (c == 0) ? 0.0f : (expf(sdist[r][c] - smx[r]) / ssum[r]);
      probs[(size_t)(r0 + r) * NCP + c] = p;
    }
  }
  if (threadIdx.x == 0) {
#pragma unroll
    for (int r = 0; r < 4; ++r) probs[(size_t)(r0 + r) * NCP + NC] = -1.0f;  // pad
  }
}

// ---------------- precompute overlap bitmask: mask[cl][b] = 1024 bits ----------------
__global__ __launch_bounds__(256) void mask_kernel(
    const float* __restrict__ boxes, u64* __restrict__ mask) {
#pragma clang fp contract(off)
  int cl = blockIdx.x >> 4;          // 151 classes
  int bb = (blockIdx.x & 15) * 64;   // 16 b-groups of 64
  __shared__ float4 sbox[NB];
  __shared__ float sarea[NB];
  for (int i = threadIdx.x; i < NB; i += 256) {
    float4 b = *(const float4*)(boxes + ((size_t)i * NC + cl) * 4);
    sbox[i] = b;
    sarea[i] = (b.z - b.x + 1.0f) * (b.w - b.y + 1.0f);
  }
  __syncthreads();
  int wv = threadIdx.x >> 6, lane = threadIdx.x & 63;
  for (int j = 0; j < 16; ++j) {
    int b = bb + wv * 16 + j;
    float4 B = sbox[b];
    float areaB = sarea[b];
    u64 myword = 0;
#pragma unroll
    for (int k = 0; k < 16; ++k) {
      int r = k * 64 + lane;
      float4 R = sbox[r];
      float ix = fminf(B.z, R.z) - fmaxf(B.x, R.x) + 1.0f;
      float iy = fminf(B.w, R.w) - fmaxf(B.y, R.y) + 1.0f;
      ix = fmaxf(ix, 0.0f);
      iy = fmaxf(iy, 0.0f);
      float inter = ix * iy;
      float uni = sarea[r] + areaB - inter;
      float iou = inter / uni;            // IEEE div — must match numpy exactly
      u64 bal = __ballot(iou >= 0.5f);
      if (lane == k) myword = bal;
    }
    if (lane < 16) mask[((size_t)cl * NB + b) * 16 + lane] = myword;
  }
}

// ---------------- greedy commit: FOUR waves, 4 rows/lane, 1 barrier/iter (r14) ----------------
template <int CTRL, int ROWMASK>
__device__ __forceinline__ float dpp_max_step(float v) {
  int x = __float_as_int(v);
  int t = __builtin_amdgcn_update_dpp(x, x, CTRL, ROWMASK, 0xf, false);
  return fmaxf(v, __int_as_float(t));
}

// canonical gfx9 wave64 max reduce; result broadcast via readlane(63)
__device__ __forceinline__ float wave_max(float v) {
  v = dpp_max_step<0x111, 0xf>(v);  // row_shr:1
  v = dpp_max_step<0x112, 0xf>(v);  // row_shr:2
  v = dpp_max_step<0x114, 0xf>(v);  // row_shr:4
  v = dpp_max_step<0x118, 0xf>(v);  // row_shr:8
  v = dpp_max_step<0x142, 0xa>(v);  // row_bcast:15
  v = dpp_max_step<0x143, 0xc>(v);  // row_bcast:31
  return __int_as_float(__builtin_amdgcn_readlane(__float_as_int(v), 63));
}

// scan a read-only probs row with zeroed-class bitmask applied; strict >, first max.
__device__ __forceinline__ void rescan_row(const float* __restrict__ pp,
                                           u64 z0, u64 z1, u64 z2,
                                           float& mo, int& ao) {
  const float4* p4 = (const float4*)pp;
  float m = 0.0f; int a = 0;
#pragma unroll 2
  for (int q = 0; q < NCP / 4; ++q) {
    float4 v = p4[q];
    u64 z = q < 16 ? z0 : (q < 32 ? z1 : z2);
    unsigned bits = (unsigned)(z >> ((q & 15) * 4)) & 0xFu;
    int c0 = q * 4;
    float vx = (bits & 1u) ? 0.0f : v.x;
    float vy = (bits & 2u) ? 0.0f : v.y;
    float vz = (bits & 4u) ? 0.0f : v.z;
    float vw = (bits & 8u) ? 0.0f : v.w;
    if (vx > m) { m = vx; a = c0; }
    if (vy > m) { m = vy; a = c0 + 1; }
    if (vz > m) { m = vz; a = c0 + 2; }
    if (vw > m) { m = vw; a = c0 + 3; }
  }
  mo = m; ao = a;
}

__global__ __launch_bounds__(256, 1) void greedy_kernel(
    const float* __restrict__ probs, const u64* __restrict__ mask,
    float* __restrict__ out_preds) {
  __shared__ u64 smask[NB * 16];      // 128 KB: prefetched argmax-class columns
  __shared__ unsigned pcls[NB];       // 4 KB: class tag of each prefetched column
  __shared__ u64 skey[2][4];          // parity-double-buffered per-wave keys

  int tid = threadIdx.x;
  int w = tid >> 6, lane = tid & 63;
  int rbase = tid << 2;               // my rows: rbase+0..3
  int widx = tid >> 4;                // my mask word index (row>>6 of my rows)
  int hsh = (tid & 15) << 2;          // shift for my 4 bits within the word

  float rm[4];
  int ra[4], cm[4];
  u64 zb0[4], zb1[4], zb2[4];
  unsigned committed = 0;

  // ---- init: scan my 4 rows; publish initial argmax class ----
#pragma unroll
  for (int r = 0; r < 4; ++r) {
    rescan_row(probs + (size_t)(rbase + r) * NCP, 0, 0, 0, rm[r], ra[r]);
    cm[r] = 0; zb0[r] = 0; zb1[r] = 0; zb2[r] = 0;
    pcls[rbase + r] = (unsigned)ra[r];
  }
  __syncthreads();

  // ---- prefetch 1024 columns (b, ra0[b]) into LDS ----
  for (int j = 0; j < NB; j += 16) {
    int col = j + (tid >> 4);
    int wd = tid & 15;
    unsigned pc = pcls[col];
    smask[(col << 4) | wd] = mask[(((size_t)pc << 10) | (size_t)col) * 16 + wd];
  }
  __syncthreads();

  for (int it = 0; it < NB; ++it) {
    int par = it & 1;

    // ---- local argmax over my 4 rows (ascending, strict > => smallest row on tie) ----
    float bv = rm[0];
    int bp = ra[0];                  // packed (r<<8)|ra
#pragma unroll
    for (int r = 1; r < 4; ++r) {
      int p = (r << 8) | ra[r];
      bool t = rm[r] > bv;
      bv = t ? rm[r] : bv;
      bp = t ? p : bp;
    }

    // ---- per-wave winner ----
    float wmax = wave_max(bv);
    u64 ball = __ballot(bv == wmax);
    int wl = __ffsll(ball) - 1;      // smallest lane = smallest row in wave
    int pw = __builtin_amdgcn_readlane(bp, wl);
    int gw = (w << 8) | (wl << 2) | (pw >> 8);   // wave-winner row
    int clw = pw & 0xff;
    unsigned ub = __float_as_uint(wmax);
    unsigned su = ((int)ub >= 0) ? (ub | 0x80000000u) : ~ub;  // monotone u32 of float
    u64 key = ((u64)su << 32) | ((u64)(NB - 1 - gw) << 8) | (unsigned)clw;
    if (lane == 0) skey[par][w] = key;
    __syncthreads();

    // ---- global winner (all waves redundantly; broadcast LDS reads) ----
    u64 k0 = skey[par][0], k1 = skey[par][1], k2 = skey[par][2], k3 = skey[par][3];
    u64 ka = k0 > k1 ? k0 : k1;
    u64 kb = k2 > k3 ? k2 : k3;
    u64 kk = ka > kb ? ka : kb;
    int b = NB - 1 - (int)((kk >> 8) & 0x3FFu);
    int cl = (int)(kk & 0xFFu);
    // endgame guard: all rows at -1 -> reference flat argmax picks (0,0)
    if ((unsigned)(kk >> 32) < 0x80000000u) cl = 0;

    // ---- mask word: issue LDS read immediately; rare uniform fallback to global ----
    u64 word = smask[(b << 4) | widx];
    unsigned pc = pcls[b];
    if ((unsigned)cl != pc) {
      word = mask[(((size_t)cl << 10) | (size_t)b) * 16 + widx];
    }
    unsigned hits = (unsigned)(word >> hsh) & 0xFu;

    // per-word bit of class cl (uniform), branch-free
    int wi = cl >> 6;
    u64 bmv = 1ull << (cl & 63);
    u64 m0 = (wi == 0) ? bmv : 0, m1 = (wi == 1) ? bmv : 0, m2 = (wi == 2) ? bmv : 0;

    bool meT = (tid == (b >> 2));
    int blo = b & 3;

    // ---- update my 4 rows ----
    unsigned need = 0;
#pragma unroll
    for (int r = 0; r < 4; ++r) {
      unsigned rb = 1u << r;
      bool hit = (hits & rb) != 0;
      if (r == blo) {                // scalar compare (blo uniform)
        if (meT) { committed |= rb; rm[r] = -1.0f; cm[r] = cl; hit = false; }
      }
      if (hit) {
        if (committed & rb) {
          // committed row: -1 everywhere except re-zeroed cols (0)
          if (rm[r] < 0.0f) { rm[r] = 0.0f; ra[r] = cl; }
          else if (cl < ra[r]) ra[r] = cl;
        } else {
          zb0[r] |= m0; zb1[r] |= m1; zb2[r] |= m2;
          if (ra[r] == cl) need |= rb;   // max may have dropped
        }
      }
    }
    // per-wave rescan branch (no barrier inside -> waves independent)
    if (__ballot(need != 0)) {
#pragma unroll
      for (int r = 0; r < 4; ++r) {
        if (need & (1u << r))
          rescan_row(probs + (size_t)(rbase + r) * NCP,
                     zb0[r], zb1[r], zb2[r], rm[r], ra[r]);
      }
    }
  }

  // ---- write commits ----
#pragma unroll
  for (int r = 0; r < 4; ++r)
    out_preds[rbase + r] = (float)cm[r];
}

// ---------------- host ----------------
extern "C" void kernel_launch(void* const* d_in, const int* in_sizes, int n_in,
                              void* d_out, int out_size, void* d_ws, size_t ws_size,
                              hipStream_t stream) {
  const float* obj_fmap = (const float*)d_in[0];  // [NB, DF]
  const float* W_out    = (const float*)d_in[1];  // [DF, NC]
  const float* b_out    = (const float*)d_in[2];  // [NC]
  const float* boxes    = (const float*)d_in[3];  // [NB, NC, 4]

  float* out_dists = (float*)d_out;            // NB*NC
  float* out_preds = (float*)d_out + NB * NC;  // NB (as float)

  float* probs = (float*)d_ws;                     // NB*NCP floats (622,592 B)
  u64*   mask  = (u64*)(probs + (size_t)NB * NCP); // NC*NB*16 u64 (19.8 MB)

  gemm_sm_kernel<<<NB / 4, 768, 0, stream>>>(obj_fmap, W_out, b_out, out_dists, probs);
  mask_kernel<<<NC * 16, 256, 0, stream>>>(boxes, mask);
  greedy_kernel<<<1, 256, 0, stream>>>(probs, mask, out_preds);
}